// Round 1
// baseline (613.398 us; speedup 1.0000x reference)
//
#include <hip/hip_runtime.h>
#include <hip/hip_bf16.h>
#include <cstdint>
#include <cstddef>

#define BB 8
#define SS 1024
#define DDIM 768
#define FFF 3072
#define EE 8

typedef __attribute__((ext_vector_type(8))) short short8;
typedef __attribute__((ext_vector_type(4))) float f32x4;

__device__ __forceinline__ unsigned short f2bf(float f) {
  unsigned u = __float_as_uint(f);
  u += 0x7FFFu + ((u >> 16) & 1u);
  return (unsigned short)(u >> 16);
}

__device__ __forceinline__ void async_ld16(const void* g, void* l) {
  __builtin_amdgcn_global_load_lds(
      (const __attribute__((address_space(1))) void*)g,
      (__attribute__((address_space(3))) void*)l, 16, 0, 0);
}

// ---------------- pooled mean over S ----------------
__global__ void pooled_kernel(const float* __restrict__ x, float* __restrict__ pooled) {
  int idx = blockIdx.x * 256 + threadIdx.x;  // B*D = 6144
  if (idx >= BB * DDIM) return;
  int b = idx / DDIM, d = idx % DDIM;
  const float* p = x + (size_t)b * SS * DDIM + d;
  float s = 0.f;
  for (int i = 0; i < SS; i++) s += p[(size_t)i * DDIM];
  pooled[idx] = s * (1.0f / SS);
}

// ---------------- router: logits, softmax, top2 ----------------
__global__ void router_kernel(const float* __restrict__ pooled,
                              const float* __restrict__ text,
                              const float* __restrict__ rw,
                              const float* __restrict__ rb,
                              float* __restrict__ probs_out,
                              int* __restrict__ topi,
                              float* __restrict__ topv) {
  __shared__ float lg[BB * EE];
  int t = threadIdx.x;  // block of 64
  if (t < BB * EE) {
    int b = t / EE, e = t % EE;
    float acc = rb[e];
    const float* pb = pooled + b * DDIM;
    const float* tb = text + b * DDIM;
    for (int i = 0; i < DDIM; i++) acc += pb[i] * rw[i * EE + e];
    for (int i = 0; i < DDIM; i++) acc += tb[i] * rw[(DDIM + i) * EE + e];
    lg[t] = acc;
  }
  __syncthreads();
  if (t < BB) {
    float p[EE];
    float mx = -1e30f;
    for (int e = 0; e < EE; e++) { p[e] = lg[t * EE + e]; mx = fmaxf(mx, p[e]); }
    float s = 0.f;
    for (int e = 0; e < EE; e++) { p[e] = expf(p[e] - mx); s += p[e]; }
    float inv = 1.f / s;
    for (int e = 0; e < EE; e++) { p[e] *= inv; probs_out[t * EE + e] = p[e]; }
    int i0 = 0; float v0 = p[0];
    for (int e = 1; e < EE; e++) if (p[e] > v0) { v0 = p[e]; i0 = e; }
    int i1 = -1; float v1 = -1e30f;
    for (int e = 0; e < EE; e++) if (e != i0 && p[e] > v1) { v1 = p[e]; i1 = e; }
    topi[t * 2] = i0; topi[t * 2 + 1] = i1;
    topv[t * 2] = v0; topv[t * 2 + 1] = v1;
  }
}

// ---------------- cast x fp32 -> bf16 ----------------
__global__ void cast_x_kernel(const float4* __restrict__ x, ushort4* __restrict__ xb, int n4) {
  int i = blockIdx.x * 256 + threadIdx.x;
  if (i >= n4) return;
  float4 v = x[i];
  ushort4 o;
  o.x = f2bf(v.x); o.y = f2bf(v.y); o.z = f2bf(v.z); o.w = f2bf(v.w);
  xb[i] = o;
}

// ---------------- tiled transpose + cast: in [E,R,C] f32 -> out [E,C,R] bf16 ----------------
__global__ void tcast_kernel(const float* __restrict__ in, unsigned short* __restrict__ out,
                             int R, int C) {
  __shared__ unsigned short t[32][33];
  int e = blockIdx.z;
  int r0 = blockIdx.y * 32, c0 = blockIdx.x * 32;
  int tx = threadIdx.x & 31, ty = threadIdx.x >> 5;  // 32 x 8
  const float* src = in + ((size_t)e * R + r0) * C + c0;
#pragma unroll
  for (int j = 0; j < 32; j += 8) t[ty + j][tx] = f2bf(src[(size_t)(ty + j) * C + tx]);
  __syncthreads();
  unsigned short* dst = out + ((size_t)e * C + c0) * R + r0;
#pragma unroll
  for (int j = 0; j < 32; j += 8) dst[(size_t)(ty + j) * R + tx] = t[tx][ty + j];
}

// ---------------- GEMM1: h = gelu(x @ W1[e] + b1[e]) * topv, bf16 out ----------------
// A: xb[b] [S, D] bf16 ; Bt: w1t[e] [FF, D] bf16 (W1 transposed) ; h: [B*2, S, FF] bf16
__global__ __launch_bounds__(256) void gemm1_kernel(
    const unsigned short* __restrict__ xb,
    const unsigned short* __restrict__ w1t,
    const float* __restrict__ b1,
    const int* __restrict__ topi,
    const float* __restrict__ topv,
    unsigned short* __restrict__ h) {
  int pair = blockIdx.z;
  int b = pair >> 1;
  int e = topi[pair];
  float tv = topv[pair];
  int m0 = blockIdx.y * 128, n0 = blockIdx.x * 128;
  const unsigned short* A = xb + (size_t)b * SS * DDIM;
  const unsigned short* Bt = w1t + (size_t)e * FFF * DDIM;
  __shared__ unsigned short As[128 * 32];
  __shared__ unsigned short Bs[128 * 32];
  int tid = threadIdx.x, wave = tid >> 6, lane = tid & 63;
  int wr = wave >> 1, wc = wave & 1;
  int srow = wave * 32 + (lane >> 2);
  int scol = (lane & 3) * 8;
  const unsigned short* ga0 = A + (size_t)(m0 + srow) * DDIM + scol;
  const unsigned short* gb0 = Bt + (size_t)(n0 + srow) * DDIM + scol;
  unsigned short* la = &As[srow * 32 + scol];
  unsigned short* lb = &Bs[srow * 32 + scol];
  f32x4 acc[4][4];
#pragma unroll
  for (int i = 0; i < 4; i++)
#pragma unroll
    for (int j = 0; j < 4; j++) acc[i][j] = (f32x4){0.f, 0.f, 0.f, 0.f};
  int arow = (wr * 64 + (lane & 15)) * 32 + (lane >> 4) * 8;
  int brow = (wc * 64 + (lane & 15)) * 32 + (lane >> 4) * 8;

  for (int kt = 0; kt < DDIM; kt += 32) {
    async_ld16(ga0 + kt, la);
    async_ld16(ga0 + kt + (size_t)16 * DDIM, la + 16 * 32);
    async_ld16(gb0 + kt, lb);
    async_ld16(gb0 + kt + (size_t)16 * DDIM, lb + 16 * 32);
    __syncthreads();
    short8 af[4], bf[4];
#pragma unroll
    for (int i = 0; i < 4; i++) af[i] = *(const short8*)&As[arow + i * 16 * 32];
#pragma unroll
    for (int j = 0; j < 4; j++) bf[j] = *(const short8*)&Bs[brow + j * 16 * 32];
#pragma unroll
    for (int i = 0; i < 4; i++)
#pragma unroll
      for (int j = 0; j < 4; j++)
        acc[i][j] = __builtin_amdgcn_mfma_f32_16x16x32_bf16(af[i], bf[j], acc[i][j], 0, 0, 0);
    __syncthreads();
  }

  unsigned short* hout = h + (size_t)pair * SS * FFF;
  int row_base = m0 + wr * 64 + (lane >> 4) * 4;
  int col_base = n0 + wc * 64 + (lane & 15);
#pragma unroll
  for (int j = 0; j < 4; j++) {
    int col = col_base + j * 16;
    float bias = b1[e * FFF + col];
#pragma unroll
    for (int i = 0; i < 4; i++) {
      int row = row_base + i * 16;
#pragma unroll
      for (int r = 0; r < 4; r++) {
        float v = acc[i][j][r] + bias;
        float u = 0.7978845608028654f * (v + 0.044715f * v * v * v);
        float ex = __expf(2.f * u);
        float th = 1.f - 2.f / (ex + 1.f);
        float g = 0.5f * v * (1.f + th);
        hout[(size_t)(row + r) * FFF + col] = f2bf(g * tv);
      }
    }
  }
}

// ---------------- GEMM2: mixed[b] = sum_k h[b,k] @ W2[e_k], fp32 out ----------------
// A: h[b*2+kk] [S, FF] bf16 ; Bt: w2t[e] [D, FF] bf16 (W2 transposed)
__global__ __launch_bounds__(256) void gemm2_kernel(
    const unsigned short* __restrict__ h,
    const unsigned short* __restrict__ w2t,
    const int* __restrict__ topi,
    float* __restrict__ mixed) {
  int b = blockIdx.z;
  int m0 = blockIdx.y * 128, n0 = blockIdx.x * 128;
  __shared__ unsigned short As[128 * 32];
  __shared__ unsigned short Bs[128 * 32];
  int tid = threadIdx.x, wave = tid >> 6, lane = tid & 63;
  int wr = wave >> 1, wc = wave & 1;
  int srow = wave * 32 + (lane >> 2);
  int scol = (lane & 3) * 8;
  unsigned short* la = &As[srow * 32 + scol];
  unsigned short* lb = &Bs[srow * 32 + scol];
  f32x4 acc[4][4];
#pragma unroll
  for (int i = 0; i < 4; i++)
#pragma unroll
    for (int j = 0; j < 4; j++) acc[i][j] = (f32x4){0.f, 0.f, 0.f, 0.f};
  int arow = (wr * 64 + (lane & 15)) * 32 + (lane >> 4) * 8;
  int brow = (wc * 64 + (lane & 15)) * 32 + (lane >> 4) * 8;

  for (int kk = 0; kk < 2; kk++) {
    int e = topi[b * 2 + kk];
    const unsigned short* A = h + (size_t)(b * 2 + kk) * SS * FFF;
    const unsigned short* Bt = w2t + (size_t)e * DDIM * FFF;
    const unsigned short* ga0 = A + (size_t)(m0 + srow) * FFF + scol;
    const unsigned short* gb0 = Bt + (size_t)(n0 + srow) * FFF + scol;
    for (int kt = 0; kt < FFF; kt += 32) {
      async_ld16(ga0 + kt, la);
      async_ld16(ga0 + kt + (size_t)16 * FFF, la + 16 * 32);
      async_ld16(gb0 + kt, lb);
      async_ld16(gb0 + kt + (size_t)16 * FFF, lb + 16 * 32);
      __syncthreads();
      short8 af[4], bf[4];
#pragma unroll
      for (int i = 0; i < 4; i++) af[i] = *(const short8*)&As[arow + i * 16 * 32];
#pragma unroll
      for (int j = 0; j < 4; j++) bf[j] = *(const short8*)&Bs[brow + j * 16 * 32];
#pragma unroll
      for (int i = 0; i < 4; i++)
#pragma unroll
        for (int j = 0; j < 4; j++)
          acc[i][j] = __builtin_amdgcn_mfma_f32_16x16x32_bf16(af[i], bf[j], acc[i][j], 0, 0, 0);
      __syncthreads();
    }
  }

  float* mout = mixed + (size_t)b * SS * DDIM;
  int row_base = m0 + wr * 64 + (lane >> 4) * 4;
  int col_base = n0 + wc * 64 + (lane & 15);
#pragma unroll
  for (int j = 0; j < 4; j++) {
    int col = col_base + j * 16;
#pragma unroll
    for (int i = 0; i < 4; i++) {
      int row = row_base + i * 16;
#pragma unroll
      for (int r = 0; r < 4; r++) {
        mout[(size_t)(row + r) * DDIM + col] = acc[i][j][r];
      }
    }
  }
}

// ---------------- LayerNorm + residual: out = x + LN(mixed + topv-weighted b2) ----------------
__global__ void ln_kernel(const float* __restrict__ x,
                          const float* __restrict__ mixed,
                          const float* __restrict__ b2,
                          const int* __restrict__ topi,
                          const float* __restrict__ topv,
                          const float* __restrict__ gamma,
                          const float* __restrict__ beta,
                          float* __restrict__ out) {
  int wave = threadIdx.x >> 6, lane = threadIdx.x & 63;
  int row = blockIdx.x * 4 + wave;  // < B*S = 8192
  int b = row >> 10;
  int e0 = topi[b * 2], e1 = topi[b * 2 + 1];
  float tv0 = topv[b * 2], tv1 = topv[b * 2 + 1];
  const float* mr = mixed + (size_t)row * DDIM;
  const float* xr = x + (size_t)row * DDIM;
  float v[12];
  float s = 0.f, s2 = 0.f;
#pragma unroll
  for (int i = 0; i < 12; i++) {
    int d = i * 64 + lane;
    float m = mr[d] + tv0 * b2[e0 * DDIM + d] + tv1 * b2[e1 * DDIM + d];
    v[i] = m; s += m; s2 += m * m;
  }
#pragma unroll
  for (int o = 32; o > 0; o >>= 1) { s += __shfl_xor(s, o); s2 += __shfl_xor(s2, o); }
  float mu = s * (1.f / DDIM);
  float var = s2 * (1.f / DDIM) - mu * mu;
  float rs = rsqrtf(var + 1e-5f);
  float* orow = out + (size_t)row * DDIM;
#pragma unroll
  for (int i = 0; i < 12; i++) {
    int d = i * 64 + lane;
    orow[d] = xr[d] + (v[i] - mu) * rs * gamma[d] + beta[d];
  }
}

extern "C" void kernel_launch(void* const* d_in, const int* in_sizes, int n_in,
                              void* d_out, int out_size, void* d_ws, size_t ws_size,
                              hipStream_t stream) {
  const float* x     = (const float*)d_in[0];
  const float* text  = (const float*)d_in[1];
  const float* W1    = (const float*)d_in[2];
  const float* b1    = (const float*)d_in[3];
  const float* W2    = (const float*)d_in[4];
  const float* b2    = (const float*)d_in[5];
  const float* rw    = (const float*)d_in[6];
  const float* rb    = (const float*)d_in[7];
  const float* gamma = (const float*)d_in[8];
  const float* beta  = (const float*)d_in[9];
  float* out   = (float*)d_out;
  float* probs = out + (size_t)BB * SS * DDIM;

  char* ws = (char*)d_ws;
  int*   topi   = (int*)ws;                       // 64 B
  float* topv   = (float*)(ws + 256);             // 64 B
  float* pooled = (float*)(ws + 512);             // 24 KB
  size_t off = 25088;                             // 256-aligned
  unsigned short* xb  = (unsigned short*)(ws + off);                 // 12.58 MB
  unsigned short* w1t = (unsigned short*)(ws + off + 12582912);      // 37.75 MB
  unsigned short* w2t = w1t + (size_t)EE * DDIM * FFF;               // 37.75 MB
  unsigned short* hbuf = w2t + (size_t)EE * DDIM * FFF;              // 100.66 MB
  // mixed aliases the xb/w1t region (both dead before gemm2 runs)
  float* mixed = (float*)(ws + off);                                 // 25.17 MB

  pooled_kernel<<<24, 256, 0, stream>>>(x, pooled);
  router_kernel<<<1, 64, 0, stream>>>(pooled, text, rw, rb, probs, topi, topv);
  cast_x_kernel<<<(BB * SS * DDIM / 4 + 255) / 256, 256, 0, stream>>>(
      (const float4*)x, (ushort4*)xb, BB * SS * DDIM / 4);
  tcast_kernel<<<dim3(FFF / 32, DDIM / 32, EE), 256, 0, stream>>>(W1, w1t, DDIM, FFF);
  tcast_kernel<<<dim3(DDIM / 32, FFF / 32, EE), 256, 0, stream>>>(W2, w2t, FFF, DDIM);
  gemm1_kernel<<<dim3(FFF / 128, SS / 128, BB * 2), 256, 0, stream>>>(
      xb, w1t, b1, topi, topv, hbuf);
  gemm2_kernel<<<dim3(DDIM / 128, SS / 128, BB), 256, 0, stream>>>(hbuf, w2t, topi, mixed);
  ln_kernel<<<(BB * SS) / 4, 256, 0, stream>>>(x, mixed, b2, topi, topv, gamma, beta, out);
}

// Round 2
// 603.606 us; speedup vs baseline: 1.0162x; 1.0162x over previous
//
#include <hip/hip_runtime.h>
#include <hip/hip_bf16.h>
#include <cstdint>
#include <cstddef>

#define BB 8
#define SS 1024
#define DDIM 768
#define FFF 3072
#define EE 8

typedef __attribute__((ext_vector_type(8))) short short8;
typedef __attribute__((ext_vector_type(4))) float f32x4;
typedef __attribute__((ext_vector_type(4))) unsigned short us4;

__device__ __forceinline__ unsigned short f2bf(float f) {
  unsigned u = __float_as_uint(f);
  u += 0x7FFFu + ((u >> 16) & 1u);
  return (unsigned short)(u >> 16);
}

__device__ __forceinline__ void async_ld16(const void* g, void* l) {
  __builtin_amdgcn_global_load_lds(
      (const __attribute__((address_space(1))) void*)g,
      (__attribute__((address_space(3))) void*)l, 16, 0, 0);
}

// ---------------- pooled mean over S ----------------
__global__ void pooled_kernel(const float* __restrict__ x, float* __restrict__ pooled) {
  int idx = blockIdx.x * 256 + threadIdx.x;  // B*D = 6144
  if (idx >= BB * DDIM) return;
  int b = idx / DDIM, d = idx % DDIM;
  const float* p = x + (size_t)b * SS * DDIM + d;
  float s = 0.f;
  for (int i = 0; i < SS; i++) s += p[(size_t)i * DDIM];
  pooled[idx] = s * (1.0f / SS);
}

// ---------------- router: logits, softmax, top2 ----------------
__global__ void router_kernel(const float* __restrict__ pooled,
                              const float* __restrict__ text,
                              const float* __restrict__ rw,
                              const float* __restrict__ rb,
                              float* __restrict__ probs_out,
                              int* __restrict__ topi,
                              float* __restrict__ topv) {
  __shared__ float lg[BB * EE];
  int t = threadIdx.x;  // block of 64
  if (t < BB * EE) {
    int b = t / EE, e = t % EE;
    float acc = rb[e];
    const float* pb = pooled + b * DDIM;
    const float* tb = text + b * DDIM;
    for (int i = 0; i < DDIM; i++) acc += pb[i] * rw[i * EE + e];
    for (int i = 0; i < DDIM; i++) acc += tb[i] * rw[(DDIM + i) * EE + e];
    lg[t] = acc;
  }
  __syncthreads();
  if (t < BB) {
    float p[EE];
    float mx = -1e30f;
    for (int e = 0; e < EE; e++) { p[e] = lg[t * EE + e]; mx = fmaxf(mx, p[e]); }
    float s = 0.f;
    for (int e = 0; e < EE; e++) { p[e] = expf(p[e] - mx); s += p[e]; }
    float inv = 1.f / s;
    for (int e = 0; e < EE; e++) { p[e] *= inv; probs_out[t * EE + e] = p[e]; }
    int i0 = 0; float v0 = p[0];
    for (int e = 1; e < EE; e++) if (p[e] > v0) { v0 = p[e]; i0 = e; }
    int i1 = -1; float v1 = -1e30f;
    for (int e = 0; e < EE; e++) if (e != i0 && p[e] > v1) { v1 = p[e]; i1 = e; }
    topi[t * 2] = i0; topi[t * 2 + 1] = i1;
    topv[t * 2] = v0; topv[t * 2 + 1] = v1;
  }
}

// ---------------- cast x fp32 -> bf16 ----------------
__global__ void cast_x_kernel(const float4* __restrict__ x, ushort4* __restrict__ xb, int n4) {
  int i = blockIdx.x * 256 + threadIdx.x;
  if (i >= n4) return;
  float4 v = x[i];
  ushort4 o;
  o.x = f2bf(v.x); o.y = f2bf(v.y); o.z = f2bf(v.z); o.w = f2bf(v.w);
  xb[i] = o;
}

// ---------------- tiled transpose + cast: in [E,R,C] f32 -> out [E,C,R] bf16 ----------------
__global__ void tcast_kernel(const float* __restrict__ in, unsigned short* __restrict__ out,
                             int R, int C) {
  __shared__ unsigned short t[32][33];
  int e = blockIdx.z;
  int r0 = blockIdx.y * 32, c0 = blockIdx.x * 32;
  int tx = threadIdx.x & 31, ty = threadIdx.x >> 5;  // 32 x 8
  const float* src = in + ((size_t)e * R + r0) * C + c0;
#pragma unroll
  for (int j = 0; j < 32; j += 8) t[ty + j][tx] = f2bf(src[(size_t)(ty + j) * C + tx]);
  __syncthreads();
  unsigned short* dst = out + ((size_t)e * C + c0) * R + r0;
#pragma unroll
  for (int j = 0; j < 32; j += 8) dst[(size_t)(ty + j) * R + tx] = t[tx][ty + j];
}

// ---------------- GEMM1 (operand-swapped): C'[f][s] = W1^T x^T -> h[s][f] ----------------
// A: w1t[e] [FF, D] bf16 ; B: xb[b] [S, D] bf16 ; h: [pair, S, FF] bf16 = gelu(.)*topv
__global__ __launch_bounds__(256) void gemm1_kernel(
    const unsigned short* __restrict__ w1t,
    const unsigned short* __restrict__ xb,
    const float* __restrict__ b1,
    const int* __restrict__ topi,
    const float* __restrict__ topv,
    unsigned short* __restrict__ h) {
  int pair = blockIdx.z;
  int b = pair >> 1;
  int e = topi[pair];
  float tv = topv[pair];
  int m0 = blockIdx.y * 128;  // FF tile (24)
  int n0 = blockIdx.x * 128;  // S tile (8)
  const unsigned short* A = w1t + (size_t)e * FFF * DDIM;
  const unsigned short* Bm = xb + (size_t)b * SS * DDIM;
  __shared__ unsigned short smem[128 * 136];  // union: As(8KB)+Bs(8KB) / ctile(34KB)
  unsigned short* As = smem;
  unsigned short* Bs = smem + 4096;
  int tid = threadIdx.x, wave = tid >> 6, lane = tid & 63;
  int wr = wave >> 1, wc = wave & 1;
  int srow = wave * 32 + (lane >> 2);
  // xor-swizzled global fetch column (LDS side stays lane-contiguous)
  int gcol = ((lane & 3) ^ ((lane >> 3) & 3)) * 8;
  const unsigned short* ga0 = A + (size_t)(m0 + srow) * DDIM + gcol;
  const unsigned short* gb0 = Bm + (size_t)(n0 + srow) * DDIM + gcol;
  unsigned short* la = &As[srow * 32 + (lane & 3) * 8];
  unsigned short* lb = &Bs[srow * 32 + (lane & 3) * 8];
  f32x4 acc[4][4];
#pragma unroll
  for (int i = 0; i < 4; i++)
#pragma unroll
    for (int j = 0; j < 4; j++) acc[i][j] = (f32x4){0.f, 0.f, 0.f, 0.f};
  int swr = (lane >> 1) & 3;
  int choff = ((lane >> 4) ^ swr) * 8;
  int abase = (wr * 64 + (lane & 15)) * 32 + choff;
  int bbase = (wc * 64 + (lane & 15)) * 32 + choff;

  for (int kt = 0; kt < DDIM; kt += 32) {
    async_ld16(ga0 + kt, la);
    async_ld16(ga0 + kt + (size_t)16 * DDIM, la + 16 * 32);
    async_ld16(gb0 + kt, lb);
    async_ld16(gb0 + kt + (size_t)16 * DDIM, lb + 16 * 32);
    __syncthreads();
    short8 af[4], bf[4];
#pragma unroll
    for (int i = 0; i < 4; i++) af[i] = *(const short8*)&As[abase + i * 16 * 32];
#pragma unroll
    for (int j = 0; j < 4; j++) bf[j] = *(const short8*)&Bs[bbase + j * 16 * 32];
#pragma unroll
    for (int i = 0; i < 4; i++)
#pragma unroll
      for (int j = 0; j < 4; j++)
        acc[i][j] = __builtin_amdgcn_mfma_f32_16x16x32_bf16(af[i], bf[j], acc[i][j], 0, 0, 0);
    __syncthreads();
  }

  // epilogue: bias + gelu + topv, pack f-contiguous quads -> LDS ctile[s][f]
  int mq = wr * 64 + (lane >> 4) * 4;  // local f quad base
  f32x4 bias[4];
#pragma unroll
  for (int i = 0; i < 4; i++) bias[i] = *(const f32x4*)&b1[e * FFF + m0 + mq + i * 16];
#pragma unroll
  for (int j = 0; j < 4; j++) {
    int nl = wc * 64 + j * 16 + (lane & 15);  // local s
#pragma unroll
    for (int i = 0; i < 4; i++) {
      us4 u;
#pragma unroll
      for (int r = 0; r < 4; r++) {
        float v = acc[i][j][r] + bias[i][r];
        float t = 0.7978845608028654f * (v + 0.044715f * v * v * v);
        float ex = __expf(2.f * t);
        float th = 1.f - 2.f / (ex + 1.f);
        float g = 0.5f * v * (1.f + th);
        u[r] = f2bf(g * tv);
      }
      *(us4*)&smem[nl * 136 + mq + i * 16] = u;
    }
  }
  __syncthreads();
  unsigned short* hout = h + (size_t)pair * SS * FFF;
#pragma unroll
  for (int it = 0; it < 8; it++) {
    int idx = it * 256 + tid;
    int row = idx >> 4, c8 = (idx & 15) * 8;
    short8 v = *(const short8*)&smem[row * 136 + c8];
    *(short8*)&hout[(size_t)(n0 + row) * FFF + m0 + c8] = v;
  }
}

// ---------------- GEMM2 (pair-split): y[pair] = h[pair] @ W2[e], fp32 ----------------
__global__ __launch_bounds__(256) void gemm2_kernel(
    const unsigned short* __restrict__ h,
    const unsigned short* __restrict__ w2t,
    const int* __restrict__ topi,
    float* __restrict__ y) {
  int pair = blockIdx.z;
  int e = topi[pair];
  int m0 = blockIdx.y * 128;  // S tile (8)
  int n0 = blockIdx.x * 128;  // D tile (6)
  const unsigned short* A = h + (size_t)pair * SS * FFF;
  const unsigned short* Bt = w2t + (size_t)e * DDIM * FFF;
  __shared__ unsigned short As[128 * 32];
  __shared__ unsigned short Bs[128 * 32];
  int tid = threadIdx.x, wave = tid >> 6, lane = tid & 63;
  int wr = wave >> 1, wc = wave & 1;
  int srow = wave * 32 + (lane >> 2);
  int gcol = ((lane & 3) ^ ((lane >> 3) & 3)) * 8;
  const unsigned short* ga0 = A + (size_t)(m0 + srow) * FFF + gcol;
  const unsigned short* gb0 = Bt + (size_t)(n0 + srow) * FFF + gcol;
  unsigned short* la = &As[srow * 32 + (lane & 3) * 8];
  unsigned short* lb = &Bs[srow * 32 + (lane & 3) * 8];
  f32x4 acc[4][4];
#pragma unroll
  for (int i = 0; i < 4; i++)
#pragma unroll
    for (int j = 0; j < 4; j++) acc[i][j] = (f32x4){0.f, 0.f, 0.f, 0.f};
  int swr = (lane >> 1) & 3;
  int choff = ((lane >> 4) ^ swr) * 8;
  int abase = (wr * 64 + (lane & 15)) * 32 + choff;
  int bbase = (wc * 64 + (lane & 15)) * 32 + choff;

  for (int kt = 0; kt < FFF; kt += 32) {
    async_ld16(ga0 + kt, la);
    async_ld16(ga0 + kt + (size_t)16 * FFF, la + 16 * 32);
    async_ld16(gb0 + kt, lb);
    async_ld16(gb0 + kt + (size_t)16 * FFF, lb + 16 * 32);
    __syncthreads();
    short8 af[4], bf[4];
#pragma unroll
    for (int i = 0; i < 4; i++) af[i] = *(const short8*)&As[abase + i * 16 * 32];
#pragma unroll
    for (int j = 0; j < 4; j++) bf[j] = *(const short8*)&Bs[bbase + j * 16 * 32];
#pragma unroll
    for (int i = 0; i < 4; i++)
#pragma unroll
      for (int j = 0; j < 4; j++)
        acc[i][j] = __builtin_amdgcn_mfma_f32_16x16x32_bf16(af[i], bf[j], acc[i][j], 0, 0, 0);
    __syncthreads();
  }

  float* yout = y + (size_t)pair * SS * DDIM;
  int row_base = m0 + wr * 64 + (lane >> 4) * 4;
  int col_base = n0 + wc * 64 + (lane & 15);
#pragma unroll
  for (int j = 0; j < 4; j++) {
    int col = col_base + j * 16;
#pragma unroll
    for (int i = 0; i < 4; i++) {
      int row = row_base + i * 16;
#pragma unroll
      for (int r = 0; r < 4; r++) {
        yout[(size_t)(row + r) * DDIM + col] = acc[i][j][r];
      }
    }
  }
}

// ---------------- LayerNorm + residual over summed pair outputs ----------------
__global__ void ln_kernel(const float* __restrict__ x,
                          const float* __restrict__ y,
                          const float* __restrict__ b2,
                          const int* __restrict__ topi,
                          const float* __restrict__ topv,
                          const float* __restrict__ gamma,
                          const float* __restrict__ beta,
                          float* __restrict__ out) {
  int wave = threadIdx.x >> 6, lane = threadIdx.x & 63;
  int row = blockIdx.x * 4 + wave;  // < B*S = 8192
  int b = row >> 10, s = row & 1023;
  int e0 = topi[b * 2], e1 = topi[b * 2 + 1];
  float tv0 = topv[b * 2], tv1 = topv[b * 2 + 1];
  const float* y0r = y + ((size_t)(b * 2) * SS + s) * DDIM;
  const float* y1r = y + ((size_t)(b * 2 + 1) * SS + s) * DDIM;
  const float* xr = x + (size_t)row * DDIM;
  float v[12];
  float sm = 0.f, s2 = 0.f;
#pragma unroll
  for (int i = 0; i < 12; i++) {
    int d = i * 64 + lane;
    float m = y0r[d] + y1r[d] + tv0 * b2[e0 * DDIM + d] + tv1 * b2[e1 * DDIM + d];
    v[i] = m; sm += m; s2 += m * m;
  }
#pragma unroll
  for (int o = 32; o > 0; o >>= 1) { sm += __shfl_xor(sm, o); s2 += __shfl_xor(s2, o); }
  float mu = sm * (1.f / DDIM);
  float var = s2 * (1.f / DDIM) - mu * mu;
  float rs = rsqrtf(var + 1e-5f);
  float* orow = out + (size_t)row * DDIM;
#pragma unroll
  for (int i = 0; i < 12; i++) {
    int d = i * 64 + lane;
    orow[d] = xr[d] + (v[i] - mu) * rs * gamma[d] + beta[d];
  }
}

extern "C" void kernel_launch(void* const* d_in, const int* in_sizes, int n_in,
                              void* d_out, int out_size, void* d_ws, size_t ws_size,
                              hipStream_t stream) {
  const float* x     = (const float*)d_in[0];
  const float* text  = (const float*)d_in[1];
  const float* W1    = (const float*)d_in[2];
  const float* b1    = (const float*)d_in[3];
  const float* W2    = (const float*)d_in[4];
  const float* b2    = (const float*)d_in[5];
  const float* rw    = (const float*)d_in[6];
  const float* rb    = (const float*)d_in[7];
  const float* gamma = (const float*)d_in[8];
  const float* beta  = (const float*)d_in[9];
  float* out   = (float*)d_out;
  float* probs = out + (size_t)BB * SS * DDIM;

  char* ws = (char*)d_ws;
  int*   topi   = (int*)ws;                       // 64 B
  float* topv   = (float*)(ws + 256);             // 64 B
  float* pooled = (float*)(ws + 512);             // 24 KB
  size_t off = 25088;                             // 256-aligned
  unsigned short* xb  = (unsigned short*)(ws + off);                 // 12.58 MB
  unsigned short* w1t = (unsigned short*)(ws + off + 12582912);      // 37.75 MB
  unsigned short* w2t = w1t + (size_t)EE * DDIM * FFF;               // 37.75 MB
  unsigned short* hbuf = w2t + (size_t)EE * DDIM * FFF;              // 100.66 MB
  // y[16][S][D] fp32 (50.33 MB) aliases xb+w1t exactly (dead before gemm2)
  float* yb = (float*)(ws + off);

  pooled_kernel<<<24, 256, 0, stream>>>(x, pooled);
  router_kernel<<<1, 64, 0, stream>>>(pooled, text, rw, rb, probs, topi, topv);
  cast_x_kernel<<<(BB * SS * DDIM / 4 + 255) / 256, 256, 0, stream>>>(
      (const float4*)x, (ushort4*)xb, BB * SS * DDIM / 4);
  tcast_kernel<<<dim3(FFF / 32, DDIM / 32, EE), 256, 0, stream>>>(W1, w1t, DDIM, FFF);
  tcast_kernel<<<dim3(DDIM / 32, FFF / 32, EE), 256, 0, stream>>>(W2, w2t, FFF, DDIM);
  gemm1_kernel<<<dim3(SS / 128, FFF / 128, BB * 2), 256, 0, stream>>>(
      w1t, xb, b1, topi, topv, hbuf);
  gemm2_kernel<<<dim3(DDIM / 128, SS / 128, BB * 2), 256, 0, stream>>>(hbuf, w2t, topi, yb);
  ln_kernel<<<(BB * SS) / 4, 256, 0, stream>>>(x, yb, b2, topi, topv, gamma, beta, out);
}

// Round 3
// 548.373 us; speedup vs baseline: 1.1186x; 1.1007x over previous
//
#include <hip/hip_runtime.h>
#include <hip/hip_bf16.h>
#include <cstdint>
#include <cstddef>

#define BB 8
#define SS 1024
#define DDIM 768
#define FFF 3072
#define EE 8

typedef __attribute__((ext_vector_type(8))) short short8;
typedef __attribute__((ext_vector_type(4))) float f32x4;
typedef __attribute__((ext_vector_type(4))) unsigned short us4;

__device__ __forceinline__ unsigned short f2bf(float f) {
  unsigned u = __float_as_uint(f);
  u += 0x7FFFu + ((u >> 16) & 1u);
  return (unsigned short)(u >> 16);
}

__device__ __forceinline__ void async_ld16(const void* g, void* l) {
  __builtin_amdgcn_global_load_lds(
      (const __attribute__((address_space(1))) void*)g,
      (__attribute__((address_space(3))) void*)l, 16, 0, 0);
}

// ---------------- pooled mean over S: grid (24 dtiles, 8 b), 256 thr ----------------
__global__ void pooled_kernel(const float* __restrict__ x, float* __restrict__ pooled) {
  __shared__ float red[256];
  int b = blockIdx.y;
  int d0 = blockIdx.x * 32;
  int t = threadIdx.x;
  int dl = t & 31, sg = t >> 5;
  const float* p = x + ((size_t)b * SS + sg) * DDIM + d0 + dl;
  float s = 0.f;
#pragma unroll 4
  for (int i = 0; i < SS / 8; i++) s += p[(size_t)i * 8 * DDIM];
  red[t] = s;
  __syncthreads();
  if (t < 32) {
    float acc = red[t];
#pragma unroll
    for (int g = 1; g < 8; g++) acc += red[g * 32 + t];
    pooled[b * DDIM + d0 + t] = acc * (1.f / SS);
  }
}

// ---------------- router: 1024 thr, 16-way split per (b,e) ----------------
__global__ void router_kernel(const float* __restrict__ pooled,
                              const float* __restrict__ text,
                              const float* __restrict__ rw,
                              const float* __restrict__ rb,
                              float* __restrict__ probs_out,
                              int* __restrict__ topi,
                              float* __restrict__ topv) {
  __shared__ float lg[BB * EE];
  int t = threadIdx.x;
  int be = t >> 4, part = t & 15;
  int b = be >> 3, e = be & 7;
  const float* pb = pooled + b * DDIM;
  const float* tb = text + b * DDIM;
  float acc = 0.f;
  int i0 = part * 96;
  for (int i = i0; i < i0 + 96; i++) {
    float f = (i < DDIM) ? pb[i] : tb[i - DDIM];
    acc += f * rw[i * EE + e];
  }
#pragma unroll
  for (int o = 8; o >= 1; o >>= 1) acc += __shfl_xor(acc, o);
  if (part == 0) lg[be] = acc + rb[e];
  __syncthreads();
  if (t < BB) {
    float p[EE];
    float mx = -1e30f;
    for (int e2 = 0; e2 < EE; e2++) { p[e2] = lg[t * EE + e2]; mx = fmaxf(mx, p[e2]); }
    float s = 0.f;
    for (int e2 = 0; e2 < EE; e2++) { p[e2] = expf(p[e2] - mx); s += p[e2]; }
    float inv = 1.f / s;
    for (int e2 = 0; e2 < EE; e2++) { p[e2] *= inv; probs_out[t * EE + e2] = p[e2]; }
    int j0 = 0; float v0 = p[0];
    for (int e2 = 1; e2 < EE; e2++) if (p[e2] > v0) { v0 = p[e2]; j0 = e2; }
    int j1 = -1; float v1 = -1e30f;
    for (int e2 = 0; e2 < EE; e2++) if (e2 != j0 && p[e2] > v1) { v1 = p[e2]; j1 = e2; }
    topi[t * 2] = j0; topi[t * 2 + 1] = j1;
    topv[t * 2] = v0; topv[t * 2 + 1] = v1;
  }
}

// ---------------- cast x fp32 -> bf16 ----------------
__global__ void cast_x_kernel(const float4* __restrict__ x, ushort4* __restrict__ xb, int n4) {
  int i = blockIdx.x * 256 + threadIdx.x;
  if (i >= n4) return;
  float4 v = x[i];
  ushort4 o;
  o.x = f2bf(v.x); o.y = f2bf(v.y); o.z = f2bf(v.z); o.w = f2bf(v.w);
  xb[i] = o;
}

// ---------------- tiled transpose + cast: in [E,R,C] f32 -> out [E,C,R] bf16 ----------------
__global__ void tcast_kernel(const float* __restrict__ in, unsigned short* __restrict__ out,
                             int R, int C) {
  __shared__ unsigned short t[32][33];
  int e = blockIdx.z;
  int r0 = blockIdx.y * 32, c0 = blockIdx.x * 32;
  int tx = threadIdx.x & 31, ty = threadIdx.x >> 5;  // 32 x 8
  const float* src = in + ((size_t)e * R + r0) * C + c0;
#pragma unroll
  for (int j = 0; j < 32; j += 8) t[ty + j][tx] = f2bf(src[(size_t)(ty + j) * C + tx]);
  __syncthreads();
  unsigned short* dst = out + ((size_t)e * C + c0) * R + r0;
#pragma unroll
  for (int j = 0; j < 32; j += 8) dst[(size_t)(ty + j) * R + tx] = t[tx][ty + j];
}

// ---------------- GEMM1: C'[f][s] = W1^T x^T -> h[s][f] = gelu(.)*topv, bf16 ----------------
// A: w1t[e] [FF, D] ; B: xb[b] [S, D] ; BK=64, XCD-chunked grid
__global__ __launch_bounds__(256) void gemm1_kernel(
    const unsigned short* __restrict__ w1t,
    const unsigned short* __restrict__ xb,
    const float* __restrict__ b1,
    const int* __restrict__ topi,
    const float* __restrict__ topv,
    unsigned short* __restrict__ h) {
  // XCD chunk remap: 3072 blocks, 8 XCDs -> XCD k owns pairs 2k,2k+1
  int lin = (blockIdx.z * 24 + blockIdx.y) * 8 + blockIdx.x;
  int nid = (lin & 7) * 384 + (lin >> 3);
  int pair = nid / 192;
  int rem = nid - pair * 192;
  int m0 = (rem >> 3) * 128;  // FF tile
  int n0 = (rem & 7) * 128;   // S tile
  int b = pair >> 1;
  int e = topi[pair];
  float tv = topv[pair];
  const unsigned short* A = w1t + (size_t)e * FFF * DDIM;
  const unsigned short* Bm = xb + (size_t)b * SS * DDIM;
  __shared__ unsigned short sm[16384];  // As0|As1|Bs0|Bs1, 8KB each
  unsigned short* As0 = sm;
  unsigned short* As1 = sm + 4096;
  unsigned short* Bs0 = sm + 8192;
  unsigned short* Bs1 = sm + 12288;
  int tid = threadIdx.x, wave = tid >> 6, lane = tid & 63;
  int wr = wave >> 1, wc = wave & 1;
  int srow = wave * 32 + (lane >> 2);
  int gcol = ((lane & 3) ^ ((lane >> 3) & 3)) * 8;  // xor-swizzled fetch col
  const unsigned short* ga0 = A + (size_t)(m0 + srow) * DDIM + gcol;
  const unsigned short* gb0 = Bm + (size_t)(n0 + srow) * DDIM + gcol;
  int lds_off = srow * 32 + (lane & 3) * 8;
  f32x4 acc[4][4];
#pragma unroll
  for (int i = 0; i < 4; i++)
#pragma unroll
    for (int j = 0; j < 4; j++) acc[i][j] = (f32x4){0.f, 0.f, 0.f, 0.f};
  int choff = (((lane >> 4) ^ ((lane >> 1) & 3))) * 8;
  int abase = (wr * 64 + (lane & 15)) * 32 + choff;
  int bbase = (wc * 64 + (lane & 15)) * 32 + choff;

  for (int kt = 0; kt < DDIM; kt += 64) {
    async_ld16(ga0 + kt, As0 + lds_off);
    async_ld16(ga0 + kt + 16 * DDIM, As0 + lds_off + 512);
    async_ld16(ga0 + kt + 32, As1 + lds_off);
    async_ld16(ga0 + kt + 32 + 16 * DDIM, As1 + lds_off + 512);
    async_ld16(gb0 + kt, Bs0 + lds_off);
    async_ld16(gb0 + kt + 16 * DDIM, Bs0 + lds_off + 512);
    async_ld16(gb0 + kt + 32, Bs1 + lds_off);
    async_ld16(gb0 + kt + 32 + 16 * DDIM, Bs1 + lds_off + 512);
    __syncthreads();
    short8 af[4], bf[4];
#pragma unroll
    for (int i = 0; i < 4; i++) af[i] = *(const short8*)&As0[abase + i * 512];
#pragma unroll
    for (int j = 0; j < 4; j++) bf[j] = *(const short8*)&Bs0[bbase + j * 512];
#pragma unroll
    for (int i = 0; i < 4; i++)
#pragma unroll
      for (int j = 0; j < 4; j++)
        acc[i][j] = __builtin_amdgcn_mfma_f32_16x16x32_bf16(af[i], bf[j], acc[i][j], 0, 0, 0);
#pragma unroll
    for (int i = 0; i < 4; i++) af[i] = *(const short8*)&As1[abase + i * 512];
#pragma unroll
    for (int j = 0; j < 4; j++) bf[j] = *(const short8*)&Bs1[bbase + j * 512];
#pragma unroll
    for (int i = 0; i < 4; i++)
#pragma unroll
      for (int j = 0; j < 4; j++)
        acc[i][j] = __builtin_amdgcn_mfma_f32_16x16x32_bf16(af[i], bf[j], acc[i][j], 0, 0, 0);
    __syncthreads();
  }

  // epilogue: bias+gelu+topv; lane quad is f-contiguous -> direct us4 (8B) stores
  unsigned short* hout = h + (size_t)pair * SS * FFF;
  int fb0 = m0 + wr * 64 + (lane >> 4) * 4;
  int sb0 = n0 + wc * 64 + (lane & 15);
  f32x4 bias[4];
#pragma unroll
  for (int i = 0; i < 4; i++) bias[i] = *(const f32x4*)&b1[e * FFF + fb0 + i * 16];
#pragma unroll
  for (int j = 0; j < 4; j++) {
    int s = sb0 + j * 16;
#pragma unroll
    for (int i = 0; i < 4; i++) {
      us4 u;
#pragma unroll
      for (int r = 0; r < 4; r++) {
        float v = acc[i][j][r] + bias[i][r];
        float t = 0.7978845608028654f * (v + 0.044715f * v * v * v);
        float ex = __expf(2.f * t);
        float th = 1.f - 2.f / (ex + 1.f);
        float g = 0.5f * v * (1.f + th);
        u[r] = f2bf(g * tv);
      }
      *(us4*)&hout[(size_t)s * FFF + fb0 + i * 16] = u;
    }
  }
}

// ---------------- GEMM2 (swapped): C'[d][s] = W2^T h^T -> y[s][d], fp32 ----------------
// A: w2t[e] [D, FF] ; B: h[pair] [S, FF] ; BK=64, XCD-chunked grid
__global__ __launch_bounds__(256) void gemm2_kernel(
    const unsigned short* __restrict__ w2t,
    const unsigned short* __restrict__ h,
    const int* __restrict__ topi,
    float* __restrict__ y) {
  // 768 blocks: XCD k owns pairs 2k,2k+1
  int lin = (blockIdx.z * 8 + blockIdx.y) * 6 + blockIdx.x;
  int nid = (lin & 7) * 96 + (lin >> 3);
  int pair = nid / 48;
  int rem = nid - pair * 48;
  int stile = rem / 6;
  int m0 = (rem - stile * 6) * 128;  // D tile
  int n0 = stile * 128;              // S tile
  int e = topi[pair];
  const unsigned short* A = w2t + (size_t)e * DDIM * FFF;
  const unsigned short* Bm = h + (size_t)pair * SS * FFF;
  __shared__ unsigned short sm[16384];
  unsigned short* As0 = sm;
  unsigned short* As1 = sm + 4096;
  unsigned short* Bs0 = sm + 8192;
  unsigned short* Bs1 = sm + 12288;
  int tid = threadIdx.x, wave = tid >> 6, lane = tid & 63;
  int wr = wave >> 1, wc = wave & 1;
  int srow = wave * 32 + (lane >> 2);
  int gcol = ((lane & 3) ^ ((lane >> 3) & 3)) * 8;
  const unsigned short* ga0 = A + (size_t)(m0 + srow) * FFF + gcol;
  const unsigned short* gb0 = Bm + (size_t)(n0 + srow) * FFF + gcol;
  int lds_off = srow * 32 + (lane & 3) * 8;
  f32x4 acc[4][4];
#pragma unroll
  for (int i = 0; i < 4; i++)
#pragma unroll
    for (int j = 0; j < 4; j++) acc[i][j] = (f32x4){0.f, 0.f, 0.f, 0.f};
  int choff = (((lane >> 4) ^ ((lane >> 1) & 3))) * 8;
  int abase = (wr * 64 + (lane & 15)) * 32 + choff;
  int bbase = (wc * 64 + (lane & 15)) * 32 + choff;

  for (int kt = 0; kt < FFF; kt += 64) {
    async_ld16(ga0 + kt, As0 + lds_off);
    async_ld16(ga0 + kt + 16 * FFF, As0 + lds_off + 512);
    async_ld16(ga0 + kt + 32, As1 + lds_off);
    async_ld16(ga0 + kt + 32 + 16 * FFF, As1 + lds_off + 512);
    async_ld16(gb0 + kt, Bs0 + lds_off);
    async_ld16(gb0 + kt + 16 * FFF, Bs0 + lds_off + 512);
    async_ld16(gb0 + kt + 32, Bs1 + lds_off);
    async_ld16(gb0 + kt + 32 + 16 * FFF, Bs1 + lds_off + 512);
    __syncthreads();
    short8 af[4], bf[4];
#pragma unroll
    for (int i = 0; i < 4; i++) af[i] = *(const short8*)&As0[abase + i * 512];
#pragma unroll
    for (int j = 0; j < 4; j++) bf[j] = *(const short8*)&Bs0[bbase + j * 512];
#pragma unroll
    for (int i = 0; i < 4; i++)
#pragma unroll
      for (int j = 0; j < 4; j++)
        acc[i][j] = __builtin_amdgcn_mfma_f32_16x16x32_bf16(af[i], bf[j], acc[i][j], 0, 0, 0);
#pragma unroll
    for (int i = 0; i < 4; i++) af[i] = *(const short8*)&As1[abase + i * 512];
#pragma unroll
    for (int j = 0; j < 4; j++) bf[j] = *(const short8*)&Bs1[bbase + j * 512];
#pragma unroll
    for (int i = 0; i < 4; i++)
#pragma unroll
      for (int j = 0; j < 4; j++)
        acc[i][j] = __builtin_amdgcn_mfma_f32_16x16x32_bf16(af[i], bf[j], acc[i][j], 0, 0, 0);
    __syncthreads();
  }

  // lane quad is d-contiguous -> direct float4 stores
  float* yout = y + (size_t)pair * SS * DDIM;
  int db0 = m0 + wr * 64 + (lane >> 4) * 4;
  int sb0 = n0 + wc * 64 + (lane & 15);
#pragma unroll
  for (int j = 0; j < 4; j++) {
    int s = sb0 + j * 16;
#pragma unroll
    for (int i = 0; i < 4; i++) {
      *(f32x4*)&yout[(size_t)s * DDIM + db0 + i * 16] = acc[i][j];
    }
  }
}

// ---------------- LayerNorm + residual over summed pair outputs ----------------
__global__ void ln_kernel(const float* __restrict__ x,
                          const float* __restrict__ y,
                          const float* __restrict__ b2,
                          const int* __restrict__ topi,
                          const float* __restrict__ topv,
                          const float* __restrict__ gamma,
                          const float* __restrict__ beta,
                          float* __restrict__ out) {
  int wave = threadIdx.x >> 6, lane = threadIdx.x & 63;
  int row = blockIdx.x * 4 + wave;  // < B*S = 8192
  int b = row >> 10, s = row & 1023;
  int e0 = topi[b * 2], e1 = topi[b * 2 + 1];
  float tv0 = topv[b * 2], tv1 = topv[b * 2 + 1];
  const float* y0r = y + ((size_t)(b * 2) * SS + s) * DDIM;
  const float* y1r = y + ((size_t)(b * 2 + 1) * SS + s) * DDIM;
  const float* xr = x + (size_t)row * DDIM;
  float v[12];
  float sm = 0.f, s2 = 0.f;
#pragma unroll
  for (int i = 0; i < 12; i++) {
    int d = i * 64 + lane;
    float m = y0r[d] + y1r[d] + tv0 * b2[e0 * DDIM + d] + tv1 * b2[e1 * DDIM + d];
    v[i] = m; sm += m; s2 += m * m;
  }
#pragma unroll
  for (int o = 32; o > 0; o >>= 1) { sm += __shfl_xor(sm, o); s2 += __shfl_xor(s2, o); }
  float mu = sm * (1.f / DDIM);
  float var = s2 * (1.f / DDIM) - mu * mu;
  float rs = rsqrtf(var + 1e-5f);
  float* orow = out + (size_t)row * DDIM;
#pragma unroll
  for (int i = 0; i < 12; i++) {
    int d = i * 64 + lane;
    orow[d] = xr[d] + (v[i] - mu) * rs * gamma[d] + beta[d];
  }
}

extern "C" void kernel_launch(void* const* d_in, const int* in_sizes, int n_in,
                              void* d_out, int out_size, void* d_ws, size_t ws_size,
                              hipStream_t stream) {
  const float* x     = (const float*)d_in[0];
  const float* text  = (const float*)d_in[1];
  const float* W1    = (const float*)d_in[2];
  const float* b1    = (const float*)d_in[3];
  const float* W2    = (const float*)d_in[4];
  const float* b2    = (const float*)d_in[5];
  const float* rw    = (const float*)d_in[6];
  const float* rb    = (const float*)d_in[7];
  const float* gamma = (const float*)d_in[8];
  const float* beta  = (const float*)d_in[9];
  float* out   = (float*)d_out;
  float* probs = out + (size_t)BB * SS * DDIM;

  char* ws = (char*)d_ws;
  int*   topi   = (int*)ws;                       // 64 B
  float* topv   = (float*)(ws + 256);             // 64 B
  float* pooled = (float*)(ws + 512);             // 24 KB
  size_t off = 25088;                             // 256-aligned
  unsigned short* xb  = (unsigned short*)(ws + off);                 // 12.58 MB
  unsigned short* w1t = (unsigned short*)(ws + off + 12582912);      // 37.75 MB
  unsigned short* w2t = w1t + (size_t)EE * DDIM * FFF;               // 37.75 MB
  unsigned short* hbuf = w2t + (size_t)EE * DDIM * FFF;              // 100.66 MB
  // y[16][S][D] fp32 (50.33 MB) aliases xb+w1t exactly (dead before gemm2)
  float* yb = (float*)(ws + off);

  pooled_kernel<<<dim3(24, 8), 256, 0, stream>>>(x, pooled);
  router_kernel<<<1, 1024, 0, stream>>>(pooled, text, rw, rb, probs, topi, topv);
  cast_x_kernel<<<(BB * SS * DDIM / 4 + 255) / 256, 256, 0, stream>>>(
      (const float4*)x, (ushort4*)xb, BB * SS * DDIM / 4);
  tcast_kernel<<<dim3(FFF / 32, DDIM / 32, EE), 256, 0, stream>>>(W1, w1t, DDIM, FFF);
  tcast_kernel<<<dim3(DDIM / 32, FFF / 32, EE), 256, 0, stream>>>(W2, w2t, FFF, DDIM);
  gemm1_kernel<<<dim3(8, 24, BB * 2), 256, 0, stream>>>(
      w1t, xb, b1, topi, topv, hbuf);
  gemm2_kernel<<<dim3(6, 8, BB * 2), 256, 0, stream>>>(w2t, hbuf, topi, yb);
  ln_kernel<<<(BB * SS) / 4, 256, 0, stream>>>(x, yb, b2, topi, topv, gamma, beta, out);
}

// Round 4
// 528.536 us; speedup vs baseline: 1.1606x; 1.0375x over previous
//
#include <hip/hip_runtime.h>
#include <hip/hip_bf16.h>
#include <cstdint>
#include <cstddef>

#define BB 8
#define SS 1024
#define DDIM 768
#define FFF 3072
#define EE 8

typedef __attribute__((ext_vector_type(8))) short short8;
typedef __attribute__((ext_vector_type(4))) float f32x4;
typedef __attribute__((ext_vector_type(4))) unsigned short us4;

__device__ __forceinline__ unsigned short f2bf(float f) {
  unsigned u = __float_as_uint(f);
  u += 0x7FFFu + ((u >> 16) & 1u);
  return (unsigned short)(u >> 16);
}

__device__ __forceinline__ void async_ld16(const void* g, void* l) {
  __builtin_amdgcn_global_load_lds(
      (const __attribute__((address_space(1))) void*)g,
      (__attribute__((address_space(3))) void*)l, 16, 0, 0);
}

// ---------------- fused prep: tcast W1 | tcast W2 | cast x | pooled ----------------
// blocks [0,4608): W1 [E,768,3072] -> w1t [E,3072,768]
// blocks [4608,9216): W2 [E,3072,768] -> w2t [E,768,3072]
// blocks [9216,12288): x f32 -> bf16 (us8)
// blocks [12288,12480): pooled mean over S
__global__ __launch_bounds__(256) void prep_kernel(
    const float* __restrict__ W1, const float* __restrict__ W2,
    const float* __restrict__ x,
    unsigned short* __restrict__ w1t, unsigned short* __restrict__ w2t,
    unsigned short* __restrict__ xb, float* __restrict__ pooled) {
  __shared__ unsigned short tile[64 * 66 + 32];
  int blk = blockIdx.x;
  int t = threadIdx.x;
  if (blk < 9216) {
    const float* src; unsigned short* dst; int R, C, r0, c0;
    if (blk < 4608) {
      int e = blk / 576, rem = blk % 576;           // 12 r-tiles x 48 c-tiles
      r0 = (rem / 48) * 64; c0 = (rem % 48) * 64;
      src = W1 + (size_t)e * DDIM * FFF; dst = w1t + (size_t)e * FFF * DDIM;
      R = DDIM; C = FFF;
    } else {
      int b2 = blk - 4608;
      int e = b2 / 576, rem = b2 % 576;             // 48 r-tiles x 12 c-tiles
      r0 = (rem / 12) * 64; c0 = (rem % 12) * 64;
      src = W2 + (size_t)e * FFF * DDIM; dst = w2t + (size_t)e * DDIM * FFF;
      R = FFF; C = DDIM;
    }
    int row = t >> 4, c4 = (t & 15) * 4;
#pragma unroll
    for (int it = 0; it < 4; it++) {
      int r = row + it * 16;
      float4 v = *(const float4*)&src[(size_t)(r0 + r) * C + c0 + c4];
      us4 u; u[0] = f2bf(v.x); u[1] = f2bf(v.y); u[2] = f2bf(v.z); u[3] = f2bf(v.w);
      *(us4*)&tile[r * 66 + c4] = u;
    }
    __syncthreads();
    int seg = (t & 7) * 8;
#pragma unroll
    for (int it = 0; it < 2; it++) {
      int crow = it * 32 + (t >> 3);
      short8 u;
#pragma unroll
      for (int j = 0; j < 8; j++) u[j] = (short)tile[(seg + j) * 66 + crow];
      *(short8*)&dst[(size_t)(c0 + crow) * R + r0 + seg] = u;
    }
  } else if (blk < 12288) {
    size_t i = ((size_t)(blk - 9216) * 256 + t) * 8;
    float4 a = *(const float4*)&x[i];
    float4 b = *(const float4*)&x[i + 4];
    short8 u;
    u[0] = f2bf(a.x); u[1] = f2bf(a.y); u[2] = f2bf(a.z); u[3] = f2bf(a.w);
    u[4] = f2bf(b.x); u[5] = f2bf(b.y); u[6] = f2bf(b.z); u[7] = f2bf(b.w);
    *(short8*)&xb[i] = u;
  } else {
    float* red = (float*)tile;
    int blk2 = blk - 12288;
    int b = blk2 / 24, d0 = (blk2 % 24) * 32;
    int dl = t & 31, sg = t >> 5;
    const float* p = x + ((size_t)b * SS + sg) * DDIM + d0 + dl;
    float s = 0.f;
#pragma unroll 4
    for (int i = 0; i < SS / 8; i++) s += p[(size_t)i * 8 * DDIM];
    red[t] = s;
    __syncthreads();
    if (t < 32) {
      float acc = red[t];
#pragma unroll
      for (int g = 1; g < 8; g++) acc += red[g * 32 + t];
      pooled[b * DDIM + d0 + t] = acc * (1.f / SS);
    }
  }
}

// ---------------- router: 1024 thr, 16-way split per (b,e) ----------------
__global__ void router_kernel(const float* __restrict__ pooled,
                              const float* __restrict__ text,
                              const float* __restrict__ rw,
                              const float* __restrict__ rb,
                              float* __restrict__ probs_out,
                              int* __restrict__ topi,
                              float* __restrict__ topv) {
  __shared__ float lg[BB * EE];
  int t = threadIdx.x;
  int be = t >> 4, part = t & 15;
  int b = be >> 3, e = be & 7;
  const float* pb = pooled + b * DDIM;
  const float* tb = text + b * DDIM;
  float acc = 0.f;
  int i0 = part * 96;
  for (int i = i0; i < i0 + 96; i++) {
    float f = (i < DDIM) ? pb[i] : tb[i - DDIM];
    acc += f * rw[i * EE + e];
  }
#pragma unroll
  for (int o = 8; o >= 1; o >>= 1) acc += __shfl_xor(acc, o);
  if (part == 0) lg[be] = acc + rb[e];
  __syncthreads();
  if (t < BB) {
    float p[EE];
    float mx = -1e30f;
    for (int e2 = 0; e2 < EE; e2++) { p[e2] = lg[t * EE + e2]; mx = fmaxf(mx, p[e2]); }
    float s = 0.f;
    for (int e2 = 0; e2 < EE; e2++) { p[e2] = expf(p[e2] - mx); s += p[e2]; }
    float inv = 1.f / s;
    for (int e2 = 0; e2 < EE; e2++) { p[e2] *= inv; probs_out[t * EE + e2] = p[e2]; }
    int j0 = 0; float v0 = p[0];
    for (int e2 = 1; e2 < EE; e2++) if (p[e2] > v0) { v0 = p[e2]; j0 = e2; }
    int j1 = -1; float v1 = -1e30f;
    for (int e2 = 0; e2 < EE; e2++) if (e2 != j0 && p[e2] > v1) { v1 = p[e2]; j1 = e2; }
    topi[t * 2] = j0; topi[t * 2 + 1] = j1;
    topv[t * 2] = v0; topv[t * 2 + 1] = v1;
  }
}

// ---------------- GEMM1: C'[f][s] = W1^T x^T -> h[s][f] = gelu(.)*topv, bf16 ----------------
__global__ __launch_bounds__(256) void gemm1_kernel(
    const unsigned short* __restrict__ w1t,
    const unsigned short* __restrict__ xb,
    const float* __restrict__ b1,
    const int* __restrict__ topi,
    const float* __restrict__ topv,
    unsigned short* __restrict__ h) {
  int lin = (blockIdx.z * 24 + blockIdx.y) * 8 + blockIdx.x;
  int nid = (lin & 7) * 384 + (lin >> 3);
  int pair = nid / 192;
  int rem = nid - pair * 192;
  int m0 = (rem >> 3) * 128;  // FF tile
  int n0 = (rem & 7) * 128;   // S tile
  int b = pair >> 1;
  int e = topi[pair];
  float tv = topv[pair];
  const unsigned short* A = w1t + (size_t)e * FFF * DDIM;
  const unsigned short* Bm = xb + (size_t)b * SS * DDIM;
  __shared__ unsigned short sm[16384];
  unsigned short* As0 = sm;
  unsigned short* As1 = sm + 4096;
  unsigned short* Bs0 = sm + 8192;
  unsigned short* Bs1 = sm + 12288;
  int tid = threadIdx.x, wave = tid >> 6, lane = tid & 63;
  int wr = wave >> 1, wc = wave & 1;
  int srow = wave * 32 + (lane >> 2);
  int gcol = ((lane & 3) ^ ((lane >> 3) & 3)) * 8;
  const unsigned short* ga0 = A + (size_t)(m0 + srow) * DDIM + gcol;
  const unsigned short* gb0 = Bm + (size_t)(n0 + srow) * DDIM + gcol;
  int lds_off = srow * 32 + (lane & 3) * 8;
  f32x4 acc[4][4];
#pragma unroll
  for (int i = 0; i < 4; i++)
#pragma unroll
    for (int j = 0; j < 4; j++) acc[i][j] = (f32x4){0.f, 0.f, 0.f, 0.f};
  int choff = (((lane >> 4) ^ ((lane >> 1) & 3))) * 8;
  int abase = (wr * 64 + (lane & 15)) * 32 + choff;
  int bbase = (wc * 64 + (lane & 15)) * 32 + choff;

  for (int kt = 0; kt < DDIM; kt += 64) {
    async_ld16(ga0 + kt, As0 + lds_off);
    async_ld16(ga0 + kt + 16 * DDIM, As0 + lds_off + 512);
    async_ld16(ga0 + kt + 32, As1 + lds_off);
    async_ld16(ga0 + kt + 32 + 16 * DDIM, As1 + lds_off + 512);
    async_ld16(gb0 + kt, Bs0 + lds_off);
    async_ld16(gb0 + kt + 16 * DDIM, Bs0 + lds_off + 512);
    async_ld16(gb0 + kt + 32, Bs1 + lds_off);
    async_ld16(gb0 + kt + 32 + 16 * DDIM, Bs1 + lds_off + 512);
    __syncthreads();
    short8 af[4], bf[4];
#pragma unroll
    for (int i = 0; i < 4; i++) af[i] = *(const short8*)&As0[abase + i * 512];
#pragma unroll
    for (int j = 0; j < 4; j++) bf[j] = *(const short8*)&Bs0[bbase + j * 512];
#pragma unroll
    for (int i = 0; i < 4; i++)
#pragma unroll
      for (int j = 0; j < 4; j++)
        acc[i][j] = __builtin_amdgcn_mfma_f32_16x16x32_bf16(af[i], bf[j], acc[i][j], 0, 0, 0);
#pragma unroll
    for (int i = 0; i < 4; i++) af[i] = *(const short8*)&As1[abase + i * 512];
#pragma unroll
    for (int j = 0; j < 4; j++) bf[j] = *(const short8*)&Bs1[bbase + j * 512];
#pragma unroll
    for (int i = 0; i < 4; i++)
#pragma unroll
      for (int j = 0; j < 4; j++)
        acc[i][j] = __builtin_amdgcn_mfma_f32_16x16x32_bf16(af[i], bf[j], acc[i][j], 0, 0, 0);
    __syncthreads();
  }

  // epilogue: gelu(v) = v * sigmoid(2u), u = 0.79788(v + 0.044715 v^3)
  unsigned short* hout = h + (size_t)pair * SS * FFF;
  int fb0 = m0 + wr * 64 + (lane >> 4) * 4;
  int sb0 = n0 + wc * 64 + (lane & 15);
  f32x4 bias[4];
#pragma unroll
  for (int i = 0; i < 4; i++) bias[i] = *(const f32x4*)&b1[e * FFF + fb0 + i * 16];
#pragma unroll
  for (int j = 0; j < 4; j++) {
    int s = sb0 + j * 16;
#pragma unroll
    for (int i = 0; i < 4; i++) {
      us4 u;
#pragma unroll
      for (int r = 0; r < 4; r++) {
        float v = acc[i][j][r] + bias[i][r];
        float v2 = v * v;
        float u2 = v * (1.5957691216057308f + 0.07135481627f * v2);  // 2u
        float ex = __expf(-u2);
        float g = v / (1.f + ex);  // v * sigmoid(2u)
        u[r] = f2bf(g * tv);
      }
      *(us4*)&hout[(size_t)s * FFF + fb0 + i * 16] = u;
    }
  }
}

// ---------------- GEMM2 (swapped): C'[d][s] = W2^T h^T -> y[s][d], fp32 ----------------
__global__ __launch_bounds__(256, 4) void gemm2_kernel(
    const unsigned short* __restrict__ w2t,
    const unsigned short* __restrict__ h,
    const int* __restrict__ topi,
    float* __restrict__ y) {
  int lin = (blockIdx.z * 8 + blockIdx.y) * 6 + blockIdx.x;
  int nid = (lin & 7) * 96 + (lin >> 3);
  int pair = nid / 48;
  int rem = nid - pair * 48;
  int stile = rem / 6;
  int m0 = (rem - stile * 6) * 128;  // D tile
  int n0 = stile * 128;              // S tile
  int e = topi[pair];
  const unsigned short* A = w2t + (size_t)e * DDIM * FFF;
  const unsigned short* Bm = h + (size_t)pair * SS * FFF;
  __shared__ unsigned short sm[16384];
  unsigned short* As0 = sm;
  unsigned short* As1 = sm + 4096;
  unsigned short* Bs0 = sm + 8192;
  unsigned short* Bs1 = sm + 12288;
  int tid = threadIdx.x, wave = tid >> 6, lane = tid & 63;
  int wr = wave >> 1, wc = wave & 1;
  int srow = wave * 32 + (lane >> 2);
  int gcol = ((lane & 3) ^ ((lane >> 3) & 3)) * 8;
  const unsigned short* ga0 = A + (size_t)(m0 + srow) * FFF + gcol;
  const unsigned short* gb0 = Bm + (size_t)(n0 + srow) * FFF + gcol;
  int lds_off = srow * 32 + (lane & 3) * 8;
  f32x4 acc[4][4];
#pragma unroll
  for (int i = 0; i < 4; i++)
#pragma unroll
    for (int j = 0; j < 4; j++) acc[i][j] = (f32x4){0.f, 0.f, 0.f, 0.f};
  int choff = (((lane >> 4) ^ ((lane >> 1) & 3))) * 8;
  int abase = (wr * 64 + (lane & 15)) * 32 + choff;
  int bbase = (wc * 64 + (lane & 15)) * 32 + choff;

  for (int kt = 0; kt < FFF; kt += 64) {
    async_ld16(ga0 + kt, As0 + lds_off);
    async_ld16(ga0 + kt + 16 * FFF, As0 + lds_off + 512);
    async_ld16(ga0 + kt + 32, As1 + lds_off);
    async_ld16(ga0 + kt + 32 + 16 * FFF, As1 + lds_off + 512);
    async_ld16(gb0 + kt, Bs0 + lds_off);
    async_ld16(gb0 + kt + 16 * FFF, Bs0 + lds_off + 512);
    async_ld16(gb0 + kt + 32, Bs1 + lds_off);
    async_ld16(gb0 + kt + 32 + 16 * FFF, Bs1 + lds_off + 512);
    __syncthreads();
    short8 af[4], bf[4];
#pragma unroll
    for (int i = 0; i < 4; i++) af[i] = *(const short8*)&As0[abase + i * 512];
#pragma unroll
    for (int j = 0; j < 4; j++) bf[j] = *(const short8*)&Bs0[bbase + j * 512];
#pragma unroll
    for (int i = 0; i < 4; i++)
#pragma unroll
      for (int j = 0; j < 4; j++)
        acc[i][j] = __builtin_amdgcn_mfma_f32_16x16x32_bf16(af[i], bf[j], acc[i][j], 0, 0, 0);
#pragma unroll
    for (int i = 0; i < 4; i++) af[i] = *(const short8*)&As1[abase + i * 512];
#pragma unroll
    for (int j = 0; j < 4; j++) bf[j] = *(const short8*)&Bs1[bbase + j * 512];
#pragma unroll
    for (int i = 0; i < 4; i++)
#pragma unroll
      for (int j = 0; j < 4; j++)
        acc[i][j] = __builtin_amdgcn_mfma_f32_16x16x32_bf16(af[i], bf[j], acc[i][j], 0, 0, 0);
    __syncthreads();
  }

  float* yout = y + (size_t)pair * SS * DDIM;
  int db0 = m0 + wr * 64 + (lane >> 4) * 4;
  int sb0 = n0 + wc * 64 + (lane & 15);
#pragma unroll
  for (int j = 0; j < 4; j++) {
    int s = sb0 + j * 16;
#pragma unroll
    for (int i = 0; i < 4; i++) {
      *(f32x4*)&yout[(size_t)s * DDIM + db0 + i * 16] = acc[i][j];
    }
  }
}

// ---------------- LayerNorm + residual over summed pair outputs ----------------
__global__ void ln_kernel(const float* __restrict__ x,
                          const float* __restrict__ y,
                          const float* __restrict__ b2,
                          const int* __restrict__ topi,
                          const float* __restrict__ topv,
                          const float* __restrict__ gamma,
                          const float* __restrict__ beta,
                          float* __restrict__ out) {
  int wave = threadIdx.x >> 6, lane = threadIdx.x & 63;
  int row = blockIdx.x * 4 + wave;  // < B*S = 8192
  int b = row >> 10, s = row & 1023;
  int e0 = topi[b * 2], e1 = topi[b * 2 + 1];
  float tv0 = topv[b * 2], tv1 = topv[b * 2 + 1];
  const float* y0r = y + ((size_t)(b * 2) * SS + s) * DDIM;
  const float* y1r = y + ((size_t)(b * 2 + 1) * SS + s) * DDIM;
  const float* xr = x + (size_t)row * DDIM;
  float v[12];
  float sm = 0.f, s2 = 0.f;
#pragma unroll
  for (int i = 0; i < 12; i++) {
    int d = i * 64 + lane;
    float m = y0r[d] + y1r[d] + tv0 * b2[e0 * DDIM + d] + tv1 * b2[e1 * DDIM + d];
    v[i] = m; sm += m; s2 += m * m;
  }
#pragma unroll
  for (int o = 32; o > 0; o >>= 1) { sm += __shfl_xor(sm, o); s2 += __shfl_xor(s2, o); }
  float mu = sm * (1.f / DDIM);
  float var = s2 * (1.f / DDIM) - mu * mu;
  float rs = rsqrtf(var + 1e-5f);
  float* orow = out + (size_t)row * DDIM;
#pragma unroll
  for (int i = 0; i < 12; i++) {
    int d = i * 64 + lane;
    orow[d] = xr[d] + (v[i] - mu) * rs * gamma[d] + beta[d];
  }
}

extern "C" void kernel_launch(void* const* d_in, const int* in_sizes, int n_in,
                              void* d_out, int out_size, void* d_ws, size_t ws_size,
                              hipStream_t stream) {
  const float* x     = (const float*)d_in[0];
  const float* text  = (const float*)d_in[1];
  const float* W1    = (const float*)d_in[2];
  const float* b1    = (const float*)d_in[3];
  const float* W2    = (const float*)d_in[4];
  const float* b2    = (const float*)d_in[5];
  const float* rw    = (const float*)d_in[6];
  const float* rb    = (const float*)d_in[7];
  const float* gamma = (const float*)d_in[8];
  const float* beta  = (const float*)d_in[9];
  float* out   = (float*)d_out;
  float* probs = out + (size_t)BB * SS * DDIM;

  char* ws = (char*)d_ws;
  int*   topi   = (int*)ws;                       // 64 B
  float* topv   = (float*)(ws + 256);             // 64 B
  float* pooled = (float*)(ws + 512);             // 24 KB
  size_t off = 25088;                             // 256-aligned
  unsigned short* xb  = (unsigned short*)(ws + off);                 // 12.58 MB
  unsigned short* w1t = (unsigned short*)(ws + off + 12582912);      // 37.75 MB
  unsigned short* w2t = w1t + (size_t)EE * DDIM * FFF;               // 37.75 MB
  unsigned short* hbuf = w2t + (size_t)EE * DDIM * FFF;              // 100.66 MB
  // y[16][S][D] fp32 (50.33 MB) aliases xb+w1t exactly (dead before gemm2)
  float* yb = (float*)(ws + off);

  prep_kernel<<<12480, 256, 0, stream>>>(W1, W2, x, w1t, w2t, xb, pooled);
  router_kernel<<<1, 1024, 0, stream>>>(pooled, text, rw, rb, probs, topi, topv);
  gemm1_kernel<<<dim3(8, 24, BB * 2), 256, 0, stream>>>(
      w1t, xb, b1, topi, topv, hbuf);
  gemm2_kernel<<<dim3(6, 8, BB * 2), 256, 0, stream>>>(w2t, hbuf, topi, yb);
  ln_kernel<<<(BB * SS) / 4, 256, 0, stream>>>(x, yb, b2, topi, topv, gamma, beta, out);
}

// Round 5
// 526.950 us; speedup vs baseline: 1.1641x; 1.0030x over previous
//
#include <hip/hip_runtime.h>
#include <hip/hip_bf16.h>
#include <cstdint>
#include <cstddef>

#define BB 8
#define SS 1024
#define DDIM 768
#define FFF 3072
#define EE 8

typedef __attribute__((ext_vector_type(8))) short short8;
typedef __attribute__((ext_vector_type(4))) float f32x4;
typedef __attribute__((ext_vector_type(4))) unsigned short us4;

__device__ __forceinline__ unsigned short f2bf(float f) {
  unsigned u = __float_as_uint(f);
  u += 0x7FFFu + ((u >> 16) & 1u);
  return (unsigned short)(u >> 16);
}

__device__ __forceinline__ void async_ld16(const void* g, void* l) {
  __builtin_amdgcn_global_load_lds(
      (const __attribute__((address_space(1))) void*)g,
      (__attribute__((address_space(3))) void*)l, 16, 0, 0);
}

// ---------------- fused prep: tcast W1 | tcast W2 | cast x | pooled ----------------
__global__ __launch_bounds__(256) void prep_kernel(
    const float* __restrict__ W1, const float* __restrict__ W2,
    const float* __restrict__ x,
    unsigned short* __restrict__ w1t, unsigned short* __restrict__ w2t,
    unsigned short* __restrict__ xb, float* __restrict__ pooled) {
  __shared__ unsigned short tile[64 * 66 + 32];
  int blk = blockIdx.x;
  int t = threadIdx.x;
  if (blk < 9216) {
    const float* src; unsigned short* dst; int R, C, r0, c0;
    if (blk < 4608) {
      int e = blk / 576, rem = blk % 576;           // 12 r-tiles x 48 c-tiles
      r0 = (rem / 48) * 64; c0 = (rem % 48) * 64;
      src = W1 + (size_t)e * DDIM * FFF; dst = w1t + (size_t)e * FFF * DDIM;
      R = DDIM; C = FFF;
    } else {
      int b2 = blk - 4608;
      int e = b2 / 576, rem = b2 % 576;             // 48 r-tiles x 12 c-tiles
      r0 = (rem / 12) * 64; c0 = (rem % 12) * 64;
      src = W2 + (size_t)e * FFF * DDIM; dst = w2t + (size_t)e * DDIM * FFF;
      R = FFF; C = DDIM;
    }
    int row = t >> 4, c4 = (t & 15) * 4;
#pragma unroll
    for (int it = 0; it < 4; it++) {
      int r = row + it * 16;
      float4 v = *(const float4*)&src[(size_t)(r0 + r) * C + c0 + c4];
      us4 u; u[0] = f2bf(v.x); u[1] = f2bf(v.y); u[2] = f2bf(v.z); u[3] = f2bf(v.w);
      *(us4*)&tile[r * 66 + c4] = u;
    }
    __syncthreads();
    int seg = (t & 7) * 8;
#pragma unroll
    for (int it = 0; it < 2; it++) {
      int crow = it * 32 + (t >> 3);
      short8 u;
#pragma unroll
      for (int j = 0; j < 8; j++) u[j] = (short)tile[(seg + j) * 66 + crow];
      *(short8*)&dst[(size_t)(c0 + crow) * R + r0 + seg] = u;
    }
  } else if (blk < 12288) {
    size_t i = ((size_t)(blk - 9216) * 256 + t) * 8;
    float4 a = *(const float4*)&x[i];
    float4 b = *(const float4*)&x[i + 4];
    short8 u;
    u[0] = f2bf(a.x); u[1] = f2bf(a.y); u[2] = f2bf(a.z); u[3] = f2bf(a.w);
    u[4] = f2bf(b.x); u[5] = f2bf(b.y); u[6] = f2bf(b.z); u[7] = f2bf(b.w);
    *(short8*)&xb[i] = u;
  } else {
    float* red = (float*)tile;
    int blk2 = blk - 12288;
    int b = blk2 / 24, d0 = (blk2 % 24) * 32;
    int dl = t & 31, sg = t >> 5;
    const float* p = x + ((size_t)b * SS + sg) * DDIM + d0 + dl;
    float s = 0.f;
#pragma unroll 4
    for (int i = 0; i < SS / 8; i++) s += p[(size_t)i * 8 * DDIM];
    red[t] = s;
    __syncthreads();
    if (t < 32) {
      float acc = red[t];
#pragma unroll
      for (int g = 1; g < 8; g++) acc += red[g * 32 + t];
      pooled[b * DDIM + d0 + t] = acc * (1.f / SS);
    }
  }
}

// ---------------- router ----------------
__global__ void router_kernel(const float* __restrict__ pooled,
                              const float* __restrict__ text,
                              const float* __restrict__ rw,
                              const float* __restrict__ rb,
                              float* __restrict__ probs_out,
                              int* __restrict__ topi,
                              float* __restrict__ topv) {
  __shared__ float lg[BB * EE];
  int t = threadIdx.x;
  int be = t >> 4, part = t & 15;
  int b = be >> 3, e = be & 7;
  const float* pb = pooled + b * DDIM;
  const float* tb = text + b * DDIM;
  float acc = 0.f;
  int i0 = part * 96;
  for (int i = i0; i < i0 + 96; i++) {
    float f = (i < DDIM) ? pb[i] : tb[i - DDIM];
    acc += f * rw[i * EE + e];
  }
#pragma unroll
  for (int o = 8; o >= 1; o >>= 1) acc += __shfl_xor(acc, o);
  if (part == 0) lg[be] = acc + rb[e];
  __syncthreads();
  if (t < BB) {
    float p[EE];
    float mx = -1e30f;
    for (int e2 = 0; e2 < EE; e2++) { p[e2] = lg[t * EE + e2]; mx = fmaxf(mx, p[e2]); }
    float s = 0.f;
    for (int e2 = 0; e2 < EE; e2++) { p[e2] = expf(p[e2] - mx); s += p[e2]; }
    float inv = 1.f / s;
    for (int e2 = 0; e2 < EE; e2++) { p[e2] *= inv; probs_out[t * EE + e2] = p[e2]; }
    int j0 = 0; float v0 = p[0];
    for (int e2 = 1; e2 < EE; e2++) if (p[e2] > v0) { v0 = p[e2]; j0 = e2; }
    int j1 = -1; float v1 = -1e30f;
    for (int e2 = 0; e2 < EE; e2++) if (e2 != j0 && p[e2] > v1) { v1 = p[e2]; j1 = e2; }
    topi[t * 2] = j0; topi[t * 2 + 1] = j1;
    topv[t * 2] = v0; topv[t * 2 + 1] = v1;
  }
}

// dbuf LDS layout per stage: A0 | A1 | B0 | B1, 4096 ush each; stage stride 16384 ush
#define PREFETCH(ga, gb, koff, stg, LDK) \
  do { \
    async_ld16((ga) + (koff), stg + lds_off); \
    async_ld16((ga) + (koff) + 16 * (LDK), stg + lds_off + 512); \
    async_ld16((ga) + (koff) + 32, stg + 4096 + lds_off); \
    async_ld16((ga) + (koff) + 32 + 16 * (LDK), stg + 4096 + lds_off + 512); \
    async_ld16((gb) + (koff), stg + 8192 + lds_off); \
    async_ld16((gb) + (koff) + 16 * (LDK), stg + 8192 + lds_off + 512); \
    async_ld16((gb) + (koff) + 32, stg + 12288 + lds_off); \
    async_ld16((gb) + (koff) + 32 + 16 * (LDK), stg + 12288 + lds_off + 512); \
  } while (0)

#define COMPUTE_STAGE(stg) \
  do { \
    short8 af[4], bf[4]; \
    _Pragma("unroll") for (int i = 0; i < 4; i++) af[i] = *(const short8*)&(stg)[abase + i * 512]; \
    _Pragma("unroll") for (int j = 0; j < 4; j++) bf[j] = *(const short8*)&(stg)[8192 + bbase + j * 512]; \
    _Pragma("unroll") for (int i = 0; i < 4; i++) \
      _Pragma("unroll") for (int j = 0; j < 4; j++) \
        acc[i][j] = __builtin_amdgcn_mfma_f32_16x16x32_bf16(af[i], bf[j], acc[i][j], 0, 0, 0); \
    _Pragma("unroll") for (int i = 0; i < 4; i++) af[i] = *(const short8*)&(stg)[4096 + abase + i * 512]; \
    _Pragma("unroll") for (int j = 0; j < 4; j++) bf[j] = *(const short8*)&(stg)[12288 + bbase + j * 512]; \
    _Pragma("unroll") for (int i = 0; i < 4; i++) \
      _Pragma("unroll") for (int j = 0; j < 4; j++) \
        acc[i][j] = __builtin_amdgcn_mfma_f32_16x16x32_bf16(af[i], bf[j], acc[i][j], 0, 0, 0); \
  } while (0)

// ---------------- GEMM1: C'[f][s] = W1^T x^T -> h[s][f] = gelu(.)*topv, bf16 ----------------
__global__ __launch_bounds__(256) void gemm1_kernel(
    const unsigned short* __restrict__ w1t,
    const unsigned short* __restrict__ xb,
    const float* __restrict__ b1,
    const int* __restrict__ topi,
    const float* __restrict__ topv,
    unsigned short* __restrict__ h) {
  int lin = (blockIdx.z * 24 + blockIdx.y) * 8 + blockIdx.x;
  int nid = (lin & 7) * 384 + (lin >> 3);
  int pair = nid / 192;
  int rem = nid - pair * 192;
  int m0 = (rem >> 3) * 128;  // FF tile
  int n0 = (rem & 7) * 128;   // S tile
  int b = pair >> 1;
  int e = topi[pair];
  float tv = topv[pair];
  const unsigned short* A = w1t + (size_t)e * FFF * DDIM;
  const unsigned short* Bm = xb + (size_t)b * SS * DDIM;
  __shared__ unsigned short sm[32768];  // 64KB: 2 stages x (A 16KB + B 16KB)
  unsigned short* st0 = sm;
  unsigned short* st1 = sm + 16384;
  int tid = threadIdx.x, wave = tid >> 6, lane = tid & 63;
  int wr = wave >> 1, wc = wave & 1;
  int srow = wave * 32 + (lane >> 2);
  int gcol = ((lane & 3) ^ ((lane >> 3) & 3)) * 8;
  const unsigned short* ga0 = A + (size_t)(m0 + srow) * DDIM + gcol;
  const unsigned short* gb0 = Bm + (size_t)(n0 + srow) * DDIM + gcol;
  int lds_off = srow * 32 + (lane & 3) * 8;
  f32x4 acc[4][4];
#pragma unroll
  for (int i = 0; i < 4; i++)
#pragma unroll
    for (int j = 0; j < 4; j++) acc[i][j] = (f32x4){0.f, 0.f, 0.f, 0.f};
  int choff = (((lane >> 4) ^ ((lane >> 1) & 3))) * 8;
  int abase = (wr * 64 + (lane & 15)) * 32 + choff;
  int bbase = (wc * 64 + (lane & 15)) * 32 + choff;

  PREFETCH(ga0, gb0, 0, st0, DDIM);
  __syncthreads();
#pragma unroll
  for (int it = 0; it < 6; it++) {
    int kt = it * 128;
    PREFETCH(ga0, gb0, kt + 64, st1, DDIM);   // kt+64 <= 704 < 768 always
    COMPUTE_STAGE(st0);
    __syncthreads();
    if (kt + 128 < DDIM) PREFETCH(ga0, gb0, kt + 128, st0, DDIM);
    COMPUTE_STAGE(st1);
    __syncthreads();
  }

  // epilogue: gelu(v) = v * sigmoid(2u)
  unsigned short* hout = h + (size_t)pair * SS * FFF;
  int fb0 = m0 + wr * 64 + (lane >> 4) * 4;
  int sb0 = n0 + wc * 64 + (lane & 15);
  f32x4 bias[4];
#pragma unroll
  for (int i = 0; i < 4; i++) bias[i] = *(const f32x4*)&b1[e * FFF + fb0 + i * 16];
#pragma unroll
  for (int j = 0; j < 4; j++) {
    int s = sb0 + j * 16;
#pragma unroll
    for (int i = 0; i < 4; i++) {
      us4 u;
#pragma unroll
      for (int r = 0; r < 4; r++) {
        float v = acc[i][j][r] + bias[i][r];
        float v2 = v * v;
        float u2 = v * (1.5957691216057308f + 0.07135481627f * v2);
        float ex = __expf(-u2);
        float g = v / (1.f + ex);
        u[r] = f2bf(g * tv);
      }
      *(us4*)&hout[(size_t)s * FFF + fb0 + i * 16] = u;
    }
  }
}

// ---------------- GEMM2 (swapped): C'[d][s] = W2^T h^T -> y[s][d], fp32 ----------------
__global__ __launch_bounds__(256) void gemm2_kernel(
    const unsigned short* __restrict__ w2t,
    const unsigned short* __restrict__ h,
    const int* __restrict__ topi,
    float* __restrict__ y) {
  int lin = (blockIdx.z * 8 + blockIdx.y) * 6 + blockIdx.x;
  int nid = (lin & 7) * 96 + (lin >> 3);
  int pair = nid / 48;
  int rem = nid - pair * 48;
  int stile = rem / 6;
  int m0 = (rem - stile * 6) * 128;  // D tile
  int n0 = stile * 128;              // S tile
  int e = topi[pair];
  const unsigned short* A = w2t + (size_t)e * DDIM * FFF;
  const unsigned short* Bm = h + (size_t)pair * SS * FFF;
  __shared__ unsigned short sm[32768];
  unsigned short* st0 = sm;
  unsigned short* st1 = sm + 16384;
  int tid = threadIdx.x, wave = tid >> 6, lane = tid & 63;
  int wr = wave >> 1, wc = wave & 1;
  int srow = wave * 32 + (lane >> 2);
  int gcol = ((lane & 3) ^ ((lane >> 3) & 3)) * 8;
  const unsigned short* ga0 = A + (size_t)(m0 + srow) * FFF + gcol;
  const unsigned short* gb0 = Bm + (size_t)(n0 + srow) * FFF + gcol;
  int lds_off = srow * 32 + (lane & 3) * 8;
  f32x4 acc[4][4];
#pragma unroll
  for (int i = 0; i < 4; i++)
#pragma unroll
    for (int j = 0; j < 4; j++) acc[i][j] = (f32x4){0.f, 0.f, 0.f, 0.f};
  int choff = (((lane >> 4) ^ ((lane >> 1) & 3))) * 8;
  int abase = (wr * 64 + (lane & 15)) * 32 + choff;
  int bbase = (wc * 64 + (lane & 15)) * 32 + choff;

  PREFETCH(ga0, gb0, 0, st0, FFF);
  __syncthreads();
#pragma unroll 1
  for (int it = 0; it < 24; it++) {
    int kt = it * 128;
    PREFETCH(ga0, gb0, kt + 64, st1, FFF);    // kt+64 <= 3008 < 3072 always
    COMPUTE_STAGE(st0);
    __syncthreads();
    if (kt + 128 < FFF) PREFETCH(ga0, gb0, kt + 128, st0, FFF);
    COMPUTE_STAGE(st1);
    __syncthreads();
  }

  float* yout = y + (size_t)pair * SS * DDIM;
  int db0 = m0 + wr * 64 + (lane >> 4) * 4;
  int sb0 = n0 + wc * 64 + (lane & 15);
#pragma unroll
  for (int j = 0; j < 4; j++) {
    int s = sb0 + j * 16;
#pragma unroll
    for (int i = 0; i < 4; i++) {
      *(f32x4*)&yout[(size_t)s * DDIM + db0 + i * 16] = acc[i][j];
    }
  }
}

// ---------------- LayerNorm + residual ----------------
__global__ void ln_kernel(const float* __restrict__ x,
                          const float* __restrict__ y,
                          const float* __restrict__ b2,
                          const int* __restrict__ topi,
                          const float* __restrict__ topv,
                          const float* __restrict__ gamma,
                          const float* __restrict__ beta,
                          float* __restrict__ out) {
  int wave = threadIdx.x >> 6, lane = threadIdx.x & 63;
  int row = blockIdx.x * 4 + wave;
  int b = row >> 10, s = row & 1023;
  int e0 = topi[b * 2], e1 = topi[b * 2 + 1];
  float tv0 = topv[b * 2], tv1 = topv[b * 2 + 1];
  const float* y0r = y + ((size_t)(b * 2) * SS + s) * DDIM;
  const float* y1r = y + ((size_t)(b * 2 + 1) * SS + s) * DDIM;
  const float* xr = x + (size_t)row * DDIM;
  float v[12];
  float sm = 0.f, s2 = 0.f;
#pragma unroll
  for (int i = 0; i < 12; i++) {
    int d = i * 64 + lane;
    float m = y0r[d] + y1r[d] + tv0 * b2[e0 * DDIM + d] + tv1 * b2[e1 * DDIM + d];
    v[i] = m; sm += m; s2 += m * m;
  }
#pragma unroll
  for (int o = 32; o > 0; o >>= 1) { sm += __shfl_xor(sm, o); s2 += __shfl_xor(s2, o); }
  float mu = sm * (1.f / DDIM);
  float var = s2 * (1.f / DDIM) - mu * mu;
  float rs = rsqrtf(var + 1e-5f);
  float* orow = out + (size_t)row * DDIM;
#pragma unroll
  for (int i = 0; i < 12; i++) {
    int d = i * 64 + lane;
    orow[d] = xr[d] + (v[i] - mu) * rs * gamma[d] + beta[d];
  }
}

extern "C" void kernel_launch(void* const* d_in, const int* in_sizes, int n_in,
                              void* d_out, int out_size, void* d_ws, size_t ws_size,
                              hipStream_t stream) {
  const float* x     = (const float*)d_in[0];
  const float* text  = (const float*)d_in[1];
  const float* W1    = (const float*)d_in[2];
  const float* b1    = (const float*)d_in[3];
  const float* W2    = (const float*)d_in[4];
  const float* b2    = (const float*)d_in[5];
  const float* rw    = (const float*)d_in[6];
  const float* rb    = (const float*)d_in[7];
  const float* gamma = (const float*)d_in[8];
  const float* beta  = (const float*)d_in[9];
  float* out   = (float*)d_out;
  float* probs = out + (size_t)BB * SS * DDIM;

  char* ws = (char*)d_ws;
  int*   topi   = (int*)ws;
  float* topv   = (float*)(ws + 256);
  float* pooled = (float*)(ws + 512);
  size_t off = 25088;
  unsigned short* xb  = (unsigned short*)(ws + off);                 // 12.58 MB
  unsigned short* w1t = (unsigned short*)(ws + off + 12582912);      // 37.75 MB
  unsigned short* w2t = w1t + (size_t)EE * DDIM * FFF;               // 37.75 MB
  unsigned short* hbuf = w2t + (size_t)EE * DDIM * FFF;              // 100.66 MB
  float* yb = (float*)(ws + off);                                    // aliases xb+w1t

  prep_kernel<<<12480, 256, 0, stream>>>(W1, W2, x, w1t, w2t, xb, pooled);
  router_kernel<<<1, 1024, 0, stream>>>(pooled, text, rw, rb, probs, topi, topv);
  gemm1_kernel<<<dim3(8, 24, BB * 2), 256, 0, stream>>>(
      w1t, xb, b1, topi, topv, hbuf);
  gemm2_kernel<<<dim3(6, 8, BB * 2), 256, 0, stream>>>(w2t, hbuf, topi, yb);
  ln_kernel<<<(BB * SS) / 4, 256, 0, stream>>>(x, yb, b2, topi, topv, gamma, beta, out);
}